// Round 3
// baseline (2333.551 us; speedup 1.0000x reference)
//
#include <hip/hip_runtime.h>
#include <hip/hip_fp16.h>

// Problem: B=256, T=512, F=64, H=128  (GRU-D / BRITS-style recurrence)
// d_out (fp32): [0]=loss, [1..256]=predictions, [257..]=imputations [B,T,F]

#define NBATCH 256
#define NT 512
#define NF 64
#define NH 128

// ---- workspace byte offsets (16B aligned) ----
#define AFRAG_OFF 0u           // [256 tiles][64 lanes] uint4: MFMA A-frags of [W_ih|W_hh]
#define WHR_OFF   262144u      // [16][64]  uint4 packed f16 chunks of W_hr   ([k4][f])
#define WFR_OFF   278528u      // [8][64]   uint4 packed f16 chunks of W_fr (diag zeroed)
#define INVMS_OFF 286720u      // f32[512]
#define ISTR_OFF  288768u      // f32[1]
#define GH_OFF    294912u      // f16 [B*T*128] gamma_h   (also reused early as msum partials)
#define AL_OFF    33849344u    // f16 [B*T*64]  alpha

typedef _Float16 half2_t __attribute__((ext_vector_type(2)));
typedef _Float16 half8_t __attribute__((ext_vector_type(8)));
typedef float float4_t __attribute__((ext_vector_type(4)));

__device__ __forceinline__ unsigned pack2(float a, float b) {
    __half2 h = __floats2half2_rn(a, b);
    return __builtin_bit_cast(unsigned, h);
}

__device__ __forceinline__ float dot2f(unsigned w, unsigned a, float acc) {
#if __has_builtin(__builtin_amdgcn_fdot2)
    return __builtin_amdgcn_fdot2(__builtin_bit_cast(half2_t, w),
                                  __builtin_bit_cast(half2_t, a), acc, false);
#else
    float2 wf = __half22float2(__builtin_bit_cast(__half2, w));
    float2 af = __half22float2(__builtin_bit_cast(__half2, a));
    return acc + wf.x * af.x + wf.y * af.y;
#endif
}

__device__ __forceinline__ float4_t mfma16(half8_t a, half8_t b, float4_t c) {
    return __builtin_amdgcn_mfma_f32_16x16x32_f16(a, b, c, 0, 0, 0);
}

__device__ __forceinline__ float sigm(float x) { return 1.f / (1.f + __expf(-x)); }
__device__ __forceinline__ float tanh_fast(float x) { return 1.f - 2.f / (__expf(2.f * x) + 1.f); }

// keep weight fragments live in registers across the loop back-edge
#define PIN4(u) asm volatile("" : "+v"((u).x), "+v"((u).y), "+v"((u).z), "+v"((u).w))

// ---------------------------------------------------------------------------
// prep_w: (a) MFMA A-frags of G=[W_ih|W_hh] (512 rows x 256 k; k=[cc,m,h]),
// tiled so wave s, gate g, chunk c -> rows 128g+16s+(lane&15), k=32c+8*(lane>>4)+2comp.
// (b) W_hr / W_fr(zero-diag) f16x2 chunk layouts [k4][f].
// ---------------------------------------------------------------------------
__global__ __launch_bounds__(256) void prep_w(const float* __restrict__ Wih,
                                              const float* __restrict__ Whh,
                                              const float* __restrict__ Whr,
                                              const float* __restrict__ Wfr,
                                              unsigned* __restrict__ wsu) {
    int o = blockIdx.x * 256 + threadIdx.x;
    float v0, v1;
    if (o < 65536) {                      // A-fragments
        int comp = o & 3;
        int u4 = o >> 2;
        int lane = u4 & 63;
        int tile = u4 >> 6;               // = (s*4+g)*8 + c
        int c = tile & 7, g = (tile >> 3) & 3, s = tile >> 5;
        int row = 128 * g + 16 * s + (lane & 15);
        int kp = 16 * c + ((lane >> 4) << 2) + comp;
        int k0 = 2 * kp;
        if (k0 < 128) { v0 = Wih[row * 128 + k0]; v1 = Wih[row * 128 + k0 + 1]; }
        else          { v0 = Whh[row * 128 + k0 - 128]; v1 = Whh[row * 128 + k0 - 127]; }
    } else if (o < 69632) {               // W_hr [64][128] -> [k4][f]
        int o3 = o - 65536;
        int c = o3 & 3, f = (o3 >> 2) & 63, cb = o3 >> 8;
        int col = 8 * cb + 2 * c;
        v0 = Whr[f * 128 + col]; v1 = Whr[f * 128 + col + 1];
    } else if (o < 71680) {               // W_fr [64][64], zero diagonal
        int o4 = o - 69632;
        int c = o4 & 3, f = (o4 >> 2) & 63, cb = o4 >> 8;
        int col = 8 * cb + 2 * c;
        v0 = (col == f) ? 0.f : Wfr[f * 64 + col];
        v1 = (col + 1 == f) ? 0.f : Wfr[f * 64 + col + 1];
    } else {
        return;
    }
    wsu[o] = pack2(v0, v1);
}

// ---------------------------------------------------------------------------
// prep_msum_part: coalesced partial mask sums. blocks<4096: t=blk>>3, bc=blk&7,
// sum masks[32bc..32bc+32)[t][:] -> part[blk]. block 4096: is_train sum -> part[4096],
// zero d_out[0].
// ---------------------------------------------------------------------------
__global__ __launch_bounds__(256) void prep_msum_part(const float* __restrict__ masks,
                                                      const float* __restrict__ is_train,
                                                      float* __restrict__ part,
                                                      float* __restrict__ d_out0) {
    __shared__ float red[256];
    int tid = threadIdx.x;
    int blk = blockIdx.x;
    if (blk < 4096) {
        int t = blk >> 3, bc = blk & 7;
        int r = tid >> 3, fo = (tid & 7) * 8;
        const float* p = masks + ((size_t)(32 * bc + r) * NT + t) * NF + fo;
        float s = 0.f;
        #pragma unroll
        for (int i = 0; i < 8; i++) s += p[i];
        red[tid] = s;
        __syncthreads();
        for (int off = 128; off > 0; off >>= 1) {
            if (tid < off) red[tid] += red[tid + off];
            __syncthreads();
        }
        if (tid == 0) part[blk] = red[0];
    } else {
        red[tid] = is_train[tid];
        __syncthreads();
        for (int off = 128; off > 0; off >>= 1) {
            if (tid < off) red[tid] += red[tid + off];
            __syncthreads();
        }
        if (tid == 0) { part[4096] = red[0]; *d_out0 = 0.f; }
    }
}

__global__ __launch_bounds__(512) void finalize_msum(const float* __restrict__ part,
                                                     float* __restrict__ invms,
                                                     float* __restrict__ inv_istr) {
    int tid = threadIdx.x;
    float s = 0.f;
    #pragma unroll
    for (int i = 0; i < 8; i++) s += part[tid * 8 + i];
    invms[tid] = 1.f / (s + 1e-5f);
    if (tid == 0) *inv_istr = 1.f / (part[4096] + 1e-5f);
}

// ---------------------------------------------------------------------------
// ga_kernel: precompute gamma_h[b,t,128] and alpha[b,t,64] (f16).
// grid 2048 x 256, 64 (b,t) pairs per block (amortize the LDS weight tables).
// ---------------------------------------------------------------------------
__global__ __launch_bounds__(256) void ga_kernel(const float* __restrict__ deltas,
                                                 const float* __restrict__ masks,
                                                 const float* __restrict__ Wdh,
                                                 const float* __restrict__ bdh,
                                                 const float* __restrict__ Wdx,
                                                 const float* __restrict__ bdx,
                                                 const float* __restrict__ Wwc,
                                                 const float* __restrict__ bwc,
                                                 __half* __restrict__ gh_all,
                                                 __half* __restrict__ al_all) {
    __shared__ unsigned wdhpk[32 * 128];   // [k2][j]
    __shared__ unsigned wwcpk[64 * 64];    // [k2][f]
    __shared__ float sbdh[128], sbdx[64], swdx[64], sbwc[64];
    __shared__ float dbuf[64];
    __shared__ __align__(16) unsigned dpk[32], gxpk[32], mpk2[32];
    int tid = threadIdx.x;

    for (int o = tid; o < 4096; o += 256) {
        int j = o & 127, k2 = o >> 7;
        wdhpk[o] = pack2(Wdh[j * 64 + 2 * k2], Wdh[j * 64 + 2 * k2 + 1]);
    }
    for (int o = tid; o < 4096; o += 256) {
        int f = o & 63, k2 = o >> 6;
        wwcpk[o] = pack2(Wwc[f * 128 + 2 * k2], Wwc[f * 128 + 2 * k2 + 1]);
    }
    if (tid < 128) sbdh[tid] = bdh[tid];
    if (tid < 64) {
        sbdx[tid] = bdx[tid];
        swdx[tid] = Wdx[tid * 65];
        sbwc[tid] = bwc[tid];
    }
    __syncthreads();

    for (int i = 0; i < 64; i++) {
        int p = blockIdx.x * 64 + i;           // p = b*T + t
        if (tid < 32) {
            float2 dv = ((const float2*)(deltas + (size_t)p * NF))[tid];
            dbuf[2 * tid] = dv.x; dbuf[2 * tid + 1] = dv.y;
            dpk[tid] = pack2(dv.x, dv.y);
        } else if (tid < 64) {
            int q = tid - 32;
            float2 mv = ((const float2*)(masks + (size_t)p * NF))[q];
            mpk2[q] = pack2(mv.x, mv.y);
        }
        __syncthreads();
        if (tid < 64) {
            float gx = __expf(-fmaxf(dbuf[tid] * swdx[tid] + sbdx[tid], 0.f));
            float oth = __shfl_xor(gx, 1);
            if (!(tid & 1)) gxpk[tid >> 1] = pack2(gx, oth);
        }
        __syncthreads();
        if (tid < 128) {
            float a0 = sbdh[tid], a1 = 0.f;
            #pragma unroll
            for (int k8 = 0; k8 < 8; k8++) {
                uint4 dp = *(const uint4*)&dpk[4 * k8];
                a0 = dot2f(wdhpk[(4 * k8 + 0) * 128 + tid], dp.x, a0);
                a1 = dot2f(wdhpk[(4 * k8 + 1) * 128 + tid], dp.y, a1);
                a0 = dot2f(wdhpk[(4 * k8 + 2) * 128 + tid], dp.z, a0);
                a1 = dot2f(wdhpk[(4 * k8 + 3) * 128 + tid], dp.w, a1);
            }
            gh_all[(size_t)p * NH + tid] = __float2half(__expf(-fmaxf(a0 + a1, 0.f)));
        } else if (tid < 192) {
            int f = tid - 128;
            float a0 = sbwc[f], a1 = 0.f;
            #pragma unroll
            for (int k8 = 0; k8 < 8; k8++) {
                uint4 gp = *(const uint4*)&gxpk[4 * k8];
                a0 = dot2f(wwcpk[(4 * k8 + 0) * 64 + f], gp.x, a0);
                a1 = dot2f(wwcpk[(4 * k8 + 1) * 64 + f], gp.y, a1);
                a0 = dot2f(wwcpk[(4 * k8 + 2) * 64 + f], gp.z, a0);
                a1 = dot2f(wwcpk[(4 * k8 + 3) * 64 + f], gp.w, a1);
            }
            #pragma unroll
            for (int k8 = 0; k8 < 8; k8++) {
                uint4 mp = *(const uint4*)&mpk2[4 * k8];
                a0 = dot2f(wwcpk[(32 + 4 * k8 + 0) * 64 + f], mp.x, a0);
                a1 = dot2f(wwcpk[(32 + 4 * k8 + 1) * 64 + f], mp.y, a1);
                a0 = dot2f(wwcpk[(32 + 4 * k8 + 2) * 64 + f], mp.z, a0);
                a1 = dot2f(wwcpk[(32 + 4 * k8 + 3) * 64 + f], mp.w, a1);
            }
            al_all[(size_t)p * NF + f] = __float2half(a0 + a1);
        }
        __syncthreads();
    }
}

// ---------------------------------------------------------------------------
// main_kernel: one block per batch element, 512 threads (8 waves), 2 barriers
// per step. Wave s owns i/f/g/o rows of LSTM elements [16s,16s+16): pointwise
// is wave-local, c-state in registers. B-operands broadcast to all 16 MFMA
// columns (every column computes the same valid result). Wave0 computes
// x_h / z_h serially with full-K fdot2 (no partial-reduce barriers).
// ---------------------------------------------------------------------------
__global__ __launch_bounds__(512, 2) void main_kernel(
    const float* __restrict__ values, const float* __restrict__ masks,
    const float* __restrict__ labels, const float* __restrict__ is_train,
    const float* __restrict__ b_hr, const float* __restrict__ b_fr,
    const float* __restrict__ b_ih, const float* __restrict__ b_hh,
    const float* __restrict__ W_out, const float* __restrict__ b_out,
    const uint4* __restrict__ afrag_ws, const uint4* __restrict__ whr_ws,
    const uint4* __restrict__ wfr_ws,
    const float* __restrict__ invms, const float* __restrict__ inv_istr,
    const __half* __restrict__ gh_all, const __half* __restrict__ al_all,
    float* __restrict__ d_out) {
    __shared__ __align__(16) uint4 whr4u[1024];      // 16 KB  [k4][f]
    __shared__ __align__(16) uint4 wfr4u[512];       // 8 KB   [k4][f]
    __shared__ __align__(16) unsigned hpk[64];       // decayed h, f16x2
    __shared__ __align__(16) unsigned ccm[64];       // [cc(32) | m(32)] f16x2
    __shared__ __align__(16) unsigned xcpk[32];      // x_c f16x2
    __shared__ float hraw[128];
    __shared__ float rbuf[128];

    const int tid = threadIdx.x;
    const int b = blockIdx.x;
    const int lane = tid & 63;
    const int s = tid >> 6;
    const int q = lane >> 4;          // 0..3
    const int l15 = lane & 15;

    // ---- A-fragments: 128 VGPRs of gate weights, loop-invariant ----
    uint4 afr[4][8];
    #pragma unroll
    for (int g = 0; g < 4; g++)
        #pragma unroll
        for (int c = 0; c < 8; c++)
            afr[g][c] = afrag_ws[(((s * 4 + g) * 8) + c) * 64 + lane];

    float4_t bias_r[4];
    #pragma unroll
    for (int g = 0; g < 4; g++)
        #pragma unroll
        for (int reg = 0; reg < 4; reg++) {
            int row = 128 * g + 16 * s + 4 * q + reg;
            bias_r[g][reg] = b_ih[row] + b_hh[row];
        }

    for (int o = tid; o < 1024; o += 512) whr4u[o] = whr_ws[o];
    if (tid < 512) wfr4u[tid] = wfr_ws[tid];
    if (tid < 64) hpk[tid] = 0u;

    const float* vp = values + (size_t)b * NT * NF;
    const float* mp = masks + (size_t)b * NT * NF;
    const __half* alp = al_all + (size_t)b * NT * NF;
    const __half* ghp = gh_all + (size_t)b * NT * NH;
    float* imp = d_out + 257 + (size_t)b * NT * NF;

    float cst[4] = {0.f, 0.f, 0.f, 0.f};   // LSTM c-state (wave-local)
    float lloss = 0.f;
    float bhr_r = 0.f, bfr_r = 0.f;
    float xr = 0.f, mr = 0.f, alr = 0.f, invr = 0.f;
    if (s == 0) {
        bhr_r = b_hr[lane]; bfr_r = b_fr[lane];
        xr = vp[lane]; mr = mp[lane];
        alr = __half2float(alp[lane]); invr = invms[0];
    }
    __syncthreads();

    for (int t = 0; t < NT; t++) {
        // re-pin the weight fragments every iteration (defeats rematerialization)
        #pragma unroll
        for (int g = 0; g < 4; g++)
            #pragma unroll
            for (int c = 0; c < 8; c++)
                PIN4(afr[g][c]);

        int tn = (t + 1 < NT) ? (t + 1) : (NT - 1);
        // gamma_h(t+1) for this wave's 4 elements (same addr per 16 lanes)
        uint2 ghn = *(const uint2*)(ghp + (size_t)tn * NH + 16 * s + 4 * q);

        // ---- h-part MFMAs (all waves, right after bar_h) ----
        float4_t acc[4];
        {
            half8_t bh[4];
            #pragma unroll
            for (int c2 = 0; c2 < 4; c2++)
                bh[c2] = *((const half8_t*)&hpk[16 * c2 + 4 * q]);
            #pragma unroll
            for (int g = 0; g < 4; g++) {
                acc[g] = bias_r[g];
                #pragma unroll
                for (int c2 = 0; c2 < 4; c2++)
                    acc[g] = mfma16(__builtin_bit_cast(half8_t, afr[g][4 + c2]), bh[c2], acc[g]);
            }
        }

        // ---- wave0 serial chain: x_h -> x_c -> z_h -> c_c ----
        if (s == 0) {
            float a0 = bhr_r, a1 = 0.f, a2 = 0.f, a3 = 0.f;
            #pragma unroll
            for (int k4 = 0; k4 < 16; k4++) {
                uint4 w = whr4u[k4 * 64 + lane];
                uint4 hp = *(const uint4*)&hpk[4 * k4];
                a0 = dot2f(w.x, hp.x, a0); a1 = dot2f(w.y, hp.y, a1);
                a2 = dot2f(w.z, hp.z, a2); a3 = dot2f(w.w, hp.w, a3);
            }
            float xh = (a0 + a1) + (a2 + a3);
            float xc = mr * xr + (1.f - mr) * xh;
            float oth = __shfl_xor(xc, 1);
            if (!(lane & 1)) xcpk[lane >> 1] = pack2(xc, oth);
            float othm = __shfl_xor(mr, 1);
            if (!(lane & 1)) ccm[32 + (lane >> 1)] = pack2(mr, othm);
            asm volatile("s_waitcnt lgkmcnt(0)" ::: "memory");   // same-wave LDS RAW

            float c0 = bfr_r, c1 = 0.f, c2 = 0.f, c3 = 0.f;
            #pragma unroll
            for (int k4 = 0; k4 < 8; k4++) {
                uint4 w = wfr4u[k4 * 64 + lane];
                uint4 xp = *(const uint4*)&xcpk[4 * k4];
                c0 = dot2f(w.x, xp.x, c0); c1 = dot2f(w.y, xp.y, c1);
                c2 = dot2f(w.z, xp.z, c2); c3 = dot2f(w.w, xp.w, c3);
            }
            float zh = (c0 + c1) + (c2 + c3);
            float ch = alr * zh + (1.f - alr) * xh;
            float cc = mr * xr + (1.f - mr) * ch;
            imp[t * NF + lane] = cc;
            lloss += (fabsf(xr - xh) + fabsf(xr - zh) + fabsf(xr - ch)) * mr * invr;
            float othc = __shfl_xor(cc, 1);
            if (!(lane & 1)) ccm[lane >> 1] = pack2(cc, othc);
        }
        __syncthreads();   // bar_cc

        // ---- wave0: prefetch next-step inputs (hidden under gates phase) ----
        if (s == 0) {
            xr = vp[tn * NF + lane]; mr = mp[tn * NF + lane];
            alr = __half2float(alp[tn * NF + lane]); invr = invms[tn];
        }

        // ---- gates cc/m-part MFMAs ----
        {
            half8_t bc2[4];
            #pragma unroll
            for (int c2 = 0; c2 < 4; c2++)
                bc2[c2] = *((const half8_t*)&ccm[16 * c2 + 4 * q]);
            #pragma unroll
            for (int g = 0; g < 4; g++) {
                #pragma unroll
                for (int c2 = 0; c2 < 4; c2++)
                    acc[g] = mfma16(__builtin_bit_cast(half8_t, afr[g][c2]), bc2[c2], acc[g]);
            }
        }

        // ---- LSTM pointwise (wave-local; every lane has valid gates) ----
        {
            float2 g01 = __half22float2(__builtin_bit_cast(__half2, ghn.x));
            float2 g23 = __half22float2(__builtin_bit_cast(__half2, ghn.y));
            float hv[4];
            #pragma unroll
            for (int reg = 0; reg < 4; reg++) {
                float gi = acc[0][reg], gf = acc[1][reg];
                float gg = acc[2][reg], go = acc[3][reg];
                float cn = sigm(gf) * cst[reg] + sigm(gi) * tanh_fast(gg);
                cst[reg] = cn;
                hv[reg] = sigm(go) * tanh_fast(cn);
            }
            if (l15 == 0) {
                *(float4*)&hraw[16 * s + 4 * q] =
                    make_float4(hv[0], hv[1], hv[2], hv[3]);
                hpk[8 * s + 2 * q] = pack2(hv[0] * g01.x, hv[1] * g01.y);
                hpk[8 * s + 2 * q + 1] = pack2(hv[2] * g23.x, hv[3] * g23.y);
            }
        }
        __syncthreads();   // bar_h
    }

    // ---- finale: y_h, prediction, loss ----
    if (tid < 128) rbuf[tid] = hraw[tid] * W_out[tid];
    __syncthreads();
    if (tid < 64) {
        float yp = rbuf[tid] + rbuf[tid + 64];
        float ll = lloss;
        #pragma unroll
        for (int off = 32; off > 0; off >>= 1) {
            ll += __shfl_down(ll, off);
            yp += __shfl_down(yp, off);
        }
        if (tid == 0) {
            float yh = yp + b_out[0];
            d_out[1 + b] = 1.f / (1.f + expf(-yh));
            float lab = labels[b], istr = is_train[b];
            float maxv = fmaxf(-yh, 0.f);
            float yl = yh - yh * lab + maxv + logf(expf(-maxv) + expf(-yh - maxv));
            atomicAdd(d_out, ll * (1.f / (float)NT) + 0.3f * yl * istr * (*inv_istr));
        }
    }
}

// ---------------------------------------------------------------------------
extern "C" void kernel_launch(void* const* d_in, const int* in_sizes, int n_in,
                              void* d_out, int out_size, void* d_ws, size_t ws_size,
                              hipStream_t stream) {
    const float* values = (const float*)d_in[0];
    const float* masks = (const float*)d_in[1];
    const float* deltas = (const float*)d_in[2];
    const float* labels = (const float*)d_in[3];
    const float* is_train = (const float*)d_in[4];
    const float* W_dh = (const float*)d_in[5];
    const float* b_dh = (const float*)d_in[6];
    const float* W_dx = (const float*)d_in[7];
    const float* b_dx = (const float*)d_in[8];
    const float* W_hr = (const float*)d_in[9];
    const float* b_hr = (const float*)d_in[10];
    const float* W_fr = (const float*)d_in[11];
    const float* b_fr = (const float*)d_in[12];
    const float* W_wc = (const float*)d_in[13];
    const float* b_wc = (const float*)d_in[14];
    const float* W_ih = (const float*)d_in[15];
    const float* b_ih = (const float*)d_in[16];
    const float* W_hh = (const float*)d_in[17];
    const float* b_hh = (const float*)d_in[18];
    const float* W_out = (const float*)d_in[19];
    const float* b_out = (const float*)d_in[20];

    char* ws = (char*)d_ws;
    unsigned* wsu = (unsigned*)d_ws;
    const uint4* afrag_ws = (const uint4*)(ws + AFRAG_OFF);
    const uint4* whr_ws = (const uint4*)(ws + WHR_OFF);
    const uint4* wfr_ws = (const uint4*)(ws + WFR_OFF);
    float* invms = (float*)(ws + INVMS_OFF);
    float* inv_istr = (float*)(ws + ISTR_OFF);
    float* part = (float*)(ws + GH_OFF);      // transient, overwritten by ga_kernel
    __half* gh_all = (__half*)(ws + GH_OFF);
    __half* al_all = (__half*)(ws + AL_OFF);
    float* out_f = (float*)d_out;

    prep_w<<<280, 256, 0, stream>>>(W_ih, W_hh, W_hr, W_fr, wsu);
    prep_msum_part<<<4097, 256, 0, stream>>>(masks, is_train, part, out_f);
    finalize_msum<<<1, 512, 0, stream>>>(part, invms, inv_istr);
    ga_kernel<<<2048, 256, 0, stream>>>(deltas, masks, W_dh, b_dh, W_dx, b_dx,
                                        W_wc, b_wc, gh_all, al_all);
    main_kernel<<<NBATCH, 512, 0, stream>>>(values, masks, labels, is_train,
                                            b_hr, b_fr, b_ih, b_hh, W_out, b_out,
                                            afrag_ws, whr_ws, wfr_ws,
                                            invms, inv_istr, gh_all, al_all, out_f);
}

// Round 4
// 1665.631 us; speedup vs baseline: 1.4010x; 1.4010x over previous
//
#include <hip/hip_runtime.h>
#include <hip/hip_fp16.h>

// Problem: B=256, T=512, F=64, H=128  (GRU-D / BRITS-style recurrence)
// d_out (fp32): [0]=loss, [1..256]=predictions, [257..]=imputations [B,T,F]

#define NBATCH 256
#define NT 512
#define NF 64
#define NH 128

// ---- workspace byte offsets (16B aligned) ----
#define AFRAG_OFF 0u           // [256 tiles][64 lanes] uint4: MFMA A-frags of [W_ih|W_hh]
#define WHR_OFF   262144u      // [16][64]  uint4 packed f16 chunks of W_hr   ([k4][f])
#define WFR_OFF   278528u      // [8][64]   uint4 packed f16 chunks of W_fr (diag zeroed)
#define INVMS_OFF 286720u      // f32[512]
#define ISTR_OFF  288768u      // f32[1]
#define MSUM_OFF  289792u      // f32[512] raw mask sums (atomic accum, zeroed by prep_w)
#define GH_OFF    294912u      // f16 [B*T*128] gamma_h
#define AL_OFF    33849344u    // f16 [B*T*64]  alpha

typedef _Float16 half2_t __attribute__((ext_vector_type(2)));
typedef _Float16 half8_t __attribute__((ext_vector_type(8)));
typedef float float4_t __attribute__((ext_vector_type(4)));

__device__ __forceinline__ unsigned pack2(float a, float b) {
    __half2 h = __floats2half2_rn(a, b);
    return __builtin_bit_cast(unsigned, h);
}

__device__ __forceinline__ float dot2f(unsigned w, unsigned a, float acc) {
#if __has_builtin(__builtin_amdgcn_fdot2)
    return __builtin_amdgcn_fdot2(__builtin_bit_cast(half2_t, w),
                                  __builtin_bit_cast(half2_t, a), acc, false);
#else
    float2 wf = __half22float2(__builtin_bit_cast(__half2, w));
    float2 af = __half22float2(__builtin_bit_cast(__half2, a));
    return acc + wf.x * af.x + wf.y * af.y;
#endif
}

__device__ __forceinline__ float4_t mfma16(half8_t a, half8_t b, float4_t c) {
    return __builtin_amdgcn_mfma_f32_16x16x32_f16(a, b, c, 0, 0, 0);
}

__device__ __forceinline__ float sigm(float x) { return 1.f / (1.f + __expf(-x)); }
__device__ __forceinline__ float tanh_fast(float x) { return 1.f - 2.f / (__expf(2.f * x) + 1.f); }

// keep weight fragments live in registers across the loop back-edge
#define PIN4(u) asm volatile("" : "+v"((u).x), "+v"((u).y), "+v"((u).z), "+v"((u).w))

// ---------------------------------------------------------------------------
// prep_w: (a) MFMA A-frags of G=[W_ih|W_hh] (512 rows x 256 k; k=[cc,m,h]),
// wave s, gate g, chunk c -> rows 128g+16s+(lane&15), k=32c+8*(lane>>4)+2comp.
// (b) W_hr / W_fr(zero-diag) f16x2 chunk layouts [k4][f].
// (c) zero msum[512] and d_out[0] (runs before ga_kernel's atomics).
// ---------------------------------------------------------------------------
__global__ __launch_bounds__(256) void prep_w(const float* __restrict__ Wih,
                                              const float* __restrict__ Whh,
                                              const float* __restrict__ Whr,
                                              const float* __restrict__ Wfr,
                                              unsigned* __restrict__ wsu,
                                              float* __restrict__ msum,
                                              float* __restrict__ d_out0) {
    int o = blockIdx.x * 256 + threadIdx.x;
    float v0, v1;
    if (o < 65536) {                      // A-fragments
        int comp = o & 3;
        int u4 = o >> 2;
        int lane = u4 & 63;
        int tile = u4 >> 6;               // = (s*4+g)*8 + c
        int c = tile & 7, g = (tile >> 3) & 3, s = tile >> 5;
        int row = 128 * g + 16 * s + (lane & 15);
        int kp = 16 * c + ((lane >> 4) << 2) + comp;
        int k0 = 2 * kp;
        if (k0 < 128) { v0 = Wih[row * 128 + k0]; v1 = Wih[row * 128 + k0 + 1]; }
        else          { v0 = Whh[row * 128 + k0 - 128]; v1 = Whh[row * 128 + k0 - 127]; }
    } else if (o < 69632) {               // W_hr [64][128] -> [k4][f]
        int o3 = o - 65536;
        int c = o3 & 3, f = (o3 >> 2) & 63, cb = o3 >> 8;
        int col = 8 * cb + 2 * c;
        v0 = Whr[f * 128 + col]; v1 = Whr[f * 128 + col + 1];
    } else if (o < 71680) {               // W_fr [64][64], zero diagonal
        int o4 = o - 69632;
        int c = o4 & 3, f = (o4 >> 2) & 63, cb = o4 >> 8;
        int col = 8 * cb + 2 * c;
        v0 = (col == f) ? 0.f : Wfr[f * 64 + col];
        v1 = (col + 1 == f) ? 0.f : Wfr[f * 64 + col + 1];
    } else {
        int idx = o - 71680;
        if (idx < 512) msum[idx] = 0.f;
        else if (idx == 512) *d_out0 = 0.f;
        return;
    }
    wsu[o] = pack2(v0, v1);
}

// ---------------------------------------------------------------------------
// finalize_msum: invms[t] = 1/(msum[t]+eps); inv_istr = 1/(sum is_train + eps).
// ---------------------------------------------------------------------------
__global__ __launch_bounds__(512) void finalize_msum(const float* __restrict__ msum,
                                                     const float* __restrict__ is_train,
                                                     float* __restrict__ invms,
                                                     float* __restrict__ inv_istr) {
    __shared__ float red[256];
    int tid = threadIdx.x;
    invms[tid] = 1.f / (msum[tid] + 1e-5f);
    if (tid < 256) red[tid] = is_train[tid];
    __syncthreads();
    for (int off = 128; off > 0; off >>= 1) {
        if (tid < off) red[tid] += red[tid + off];
        __syncthreads();
    }
    if (tid == 0) *inv_istr = 1.f / (red[0] + 1e-5f);
}

// ---------------------------------------------------------------------------
// ga_kernel: precompute gamma_h[b,t,128], alpha[b,t,64] (f16), and atomically
// accumulate per-t mask sums. grid 2048 x 256, 64 (b,t) pairs per block.
// ---------------------------------------------------------------------------
__global__ __launch_bounds__(256) void ga_kernel(const float* __restrict__ deltas,
                                                 const float* __restrict__ masks,
                                                 const float* __restrict__ Wdh,
                                                 const float* __restrict__ bdh,
                                                 const float* __restrict__ Wdx,
                                                 const float* __restrict__ bdx,
                                                 const float* __restrict__ Wwc,
                                                 const float* __restrict__ bwc,
                                                 __half* __restrict__ gh_all,
                                                 __half* __restrict__ al_all,
                                                 float* __restrict__ msum) {
    __shared__ unsigned wdhpk[32 * 128];   // [k2][j]
    __shared__ unsigned wwcpk[64 * 64];    // [k2][f]
    __shared__ float sbdh[128], sbdx[64], swdx[64], sbwc[64];
    __shared__ float dbuf[64];
    __shared__ __align__(16) unsigned dpk[32], gxpk[32], mpk2[32];
    int tid = threadIdx.x;

    for (int o = tid; o < 4096; o += 256) {
        int j = o & 127, k2 = o >> 7;
        wdhpk[o] = pack2(Wdh[j * 64 + 2 * k2], Wdh[j * 64 + 2 * k2 + 1]);
    }
    for (int o = tid; o < 4096; o += 256) {
        int f = o & 63, k2 = o >> 6;
        wwcpk[o] = pack2(Wwc[f * 128 + 2 * k2], Wwc[f * 128 + 2 * k2 + 1]);
    }
    if (tid < 128) sbdh[tid] = bdh[tid];
    if (tid < 64) {
        sbdx[tid] = bdx[tid];
        swdx[tid] = Wdx[tid * 65];
        sbwc[tid] = bwc[tid];
    }
    __syncthreads();

    for (int i = 0; i < 64; i++) {
        int p = blockIdx.x * 64 + i;           // p = b*T + t
        if (tid < 32) {
            float2 dv = ((const float2*)(deltas + (size_t)p * NF))[tid];
            dbuf[2 * tid] = dv.x; dbuf[2 * tid + 1] = dv.y;
            dpk[tid] = pack2(dv.x, dv.y);
        } else if (tid < 64) {
            int q = tid - 32;
            float2 mv = ((const float2*)(masks + (size_t)p * NF))[q];
            mpk2[q] = pack2(mv.x, mv.y);
            float sm = mv.x + mv.y;            // per-t mask sum (ints: order-safe)
            #pragma unroll
            for (int off = 16; off > 0; off >>= 1) sm += __shfl_xor(sm, off);
            if (tid == 32) atomicAdd(&msum[p & (NT - 1)], sm);
        }
        __syncthreads();
        if (tid < 64) {
            float gx = __expf(-fmaxf(dbuf[tid] * swdx[tid] + sbdx[tid], 0.f));
            float oth = __shfl_xor(gx, 1);
            if (!(tid & 1)) gxpk[tid >> 1] = pack2(gx, oth);
        }
        __syncthreads();
        if (tid < 128) {
            float a0 = sbdh[tid], a1 = 0.f;
            #pragma unroll
            for (int k8 = 0; k8 < 8; k8++) {
                uint4 dp = *(const uint4*)&dpk[4 * k8];
                a0 = dot2f(wdhpk[(4 * k8 + 0) * 128 + tid], dp.x, a0);
                a1 = dot2f(wdhpk[(4 * k8 + 1) * 128 + tid], dp.y, a1);
                a0 = dot2f(wdhpk[(4 * k8 + 2) * 128 + tid], dp.z, a0);
                a1 = dot2f(wdhpk[(4 * k8 + 3) * 128 + tid], dp.w, a1);
            }
            gh_all[(size_t)p * NH + tid] = __float2half(__expf(-fmaxf(a0 + a1, 0.f)));
        } else if (tid < 192) {
            int f = tid - 128;
            float a0 = sbwc[f], a1 = 0.f;
            #pragma unroll
            for (int k8 = 0; k8 < 8; k8++) {
                uint4 gp = *(const uint4*)&gxpk[4 * k8];
                a0 = dot2f(wwcpk[(4 * k8 + 0) * 64 + f], gp.x, a0);
                a1 = dot2f(wwcpk[(4 * k8 + 1) * 64 + f], gp.y, a1);
                a0 = dot2f(wwcpk[(4 * k8 + 2) * 64 + f], gp.z, a0);
                a1 = dot2f(wwcpk[(4 * k8 + 3) * 64 + f], gp.w, a1);
            }
            #pragma unroll
            for (int k8 = 0; k8 < 8; k8++) {
                uint4 mp = *(const uint4*)&mpk2[4 * k8];
                a0 = dot2f(wwcpk[(32 + 4 * k8 + 0) * 64 + f], mp.x, a0);
                a1 = dot2f(wwcpk[(32 + 4 * k8 + 1) * 64 + f], mp.y, a1);
                a0 = dot2f(wwcpk[(32 + 4 * k8 + 2) * 64 + f], mp.z, a0);
                a1 = dot2f(wwcpk[(32 + 4 * k8 + 3) * 64 + f], mp.w, a1);
            }
            al_all[(size_t)p * NF + f] = __float2half(a0 + a1);
        }
        __syncthreads();
    }
}

// ---------------------------------------------------------------------------
// main_kernel: one block per batch element, 512 threads (8 waves), 2 barriers
// per step. amdgpu_waves_per_eu(2,2) raises the VGPR budget to 256 so the
// 128 dwords of gate weights stay resident (R2/R3 failure mode: allocator
// heuristic capped at 128 regs -> remat/spill). Waves 1-7 run h-part MFMAs
// while wave0 runs the serial x_h->z_h chain; wave0 stashes its B-fragments
// pre-barrier and issues all 32 MFMAs post-barrier.
// ---------------------------------------------------------------------------
__global__ __attribute__((amdgpu_waves_per_eu(2, 2))) __launch_bounds__(512)
void main_kernel(
    const float* __restrict__ values, const float* __restrict__ masks,
    const float* __restrict__ labels, const float* __restrict__ is_train,
    const float* __restrict__ b_hr, const float* __restrict__ b_fr,
    const float* __restrict__ b_ih, const float* __restrict__ b_hh,
    const float* __restrict__ W_out, const float* __restrict__ b_out,
    const uint4* __restrict__ afrag_ws, const uint4* __restrict__ whr_ws,
    const uint4* __restrict__ wfr_ws,
    const float* __restrict__ invms, const float* __restrict__ inv_istr,
    const __half* __restrict__ gh_all, const __half* __restrict__ al_all,
    float* __restrict__ d_out) {
    __shared__ __align__(16) uint4 whr4u[1024];      // 16 KB  [k4][f]
    __shared__ __align__(16) uint4 wfr4u[512];       // 8 KB   [k4][f]
    __shared__ __align__(16) unsigned hpk[64];       // decayed h, f16x2
    __shared__ __align__(16) unsigned ccm[64];       // [cc(32) | m(32)] f16x2
    __shared__ __align__(16) unsigned xcpk[32];      // x_c f16x2
    __shared__ float hraw[128];
    __shared__ float rbuf[128];

    const int tid = threadIdx.x;
    const int b = blockIdx.x;
    const int lane = tid & 63;
    const int s = tid >> 6;
    const int q = lane >> 4;          // 0..3
    const int l15 = lane & 15;

    // ---- A-fragments: 128 VGPRs of gate weights, loop-invariant ----
    uint4 afr[4][8];
    #pragma unroll
    for (int g = 0; g < 4; g++)
        #pragma unroll
        for (int c = 0; c < 8; c++)
            afr[g][c] = afrag_ws[(((s * 4 + g) * 8) + c) * 64 + lane];

    float4_t bias_r[4];
    #pragma unroll
    for (int g = 0; g < 4; g++)
        #pragma unroll
        for (int reg = 0; reg < 4; reg++) {
            int row = 128 * g + 16 * s + 4 * q + reg;
            bias_r[g][reg] = b_ih[row] + b_hh[row];
        }

    for (int o = tid; o < 1024; o += 512) whr4u[o] = whr_ws[o];
    if (tid < 512) wfr4u[tid] = wfr_ws[tid];
    if (tid < 64) hpk[tid] = 0u;

    const float* vp = values + (size_t)b * NT * NF;
    const float* mp = masks + (size_t)b * NT * NF;
    const __half* alp = al_all + (size_t)b * NT * NF;
    const __half* ghp = gh_all + (size_t)b * NT * NH;
    float* imp = d_out + 257 + (size_t)b * NT * NF;

    float cst[4] = {0.f, 0.f, 0.f, 0.f};   // LSTM c-state (wave-local)
    float lloss = 0.f;
    float bhr_r = 0.f, bfr_r = 0.f;
    float xr = 0.f, mr = 0.f, alr = 0.f, invr = 0.f;
    if (s == 0) {
        bhr_r = b_hr[lane]; bfr_r = b_fr[lane];
        xr = vp[lane]; mr = mp[lane];
        alr = __half2float(alp[lane]); invr = invms[0];
    }
    __syncthreads();

    for (int t = 0; t < NT; t++) {
        // re-pin the weight fragments (no-op when the 256-reg budget holds)
        #pragma unroll
        for (int g = 0; g < 4; g++)
            #pragma unroll
            for (int c = 0; c < 8; c++)
                PIN4(afr[g][c]);

        int tn = (t + 1 < NT) ? (t + 1) : (NT - 1);
        // gamma_h(t+1) for this wave's 4 elements (quad-uniform address)
        uint2 ghn = *(const uint2*)(ghp + (size_t)tn * NH + 16 * s + 4 * q);

        float4_t acc[4];
        half8_t bh0[4];
        if (s != 0) {
            // ---- waves 1-7: h-part MFMAs (overlap wave0's serial chain) ----
            half8_t bh[4];
            #pragma unroll
            for (int c2 = 0; c2 < 4; c2++)
                bh[c2] = *((const half8_t*)&hpk[16 * c2 + 4 * q]);
            #pragma unroll
            for (int g = 0; g < 4; g++) {
                acc[g] = bias_r[g];
                #pragma unroll
                for (int c2 = 0; c2 < 4; c2++)
                    acc[g] = mfma16(__builtin_bit_cast(half8_t, afr[g][4 + c2]), bh[c2], acc[g]);
            }
        } else {
            // ---- wave0 serial chain: x_h -> x_c -> z_h -> c_c ----
            float a0 = bhr_r, a1 = 0.f, a2 = 0.f, a3 = 0.f;
            #pragma unroll
            for (int k4 = 0; k4 < 16; k4++) {
                uint4 w = whr4u[k4 * 64 + lane];
                uint4 hp = *(const uint4*)&hpk[4 * k4];
                a0 = dot2f(w.x, hp.x, a0); a1 = dot2f(w.y, hp.y, a1);
                a2 = dot2f(w.z, hp.z, a2); a3 = dot2f(w.w, hp.w, a3);
            }
            float xh = (a0 + a1) + (a2 + a3);
            float xc = mr * xr + (1.f - mr) * xh;
            float oth = __shfl_xor(xc, 1);
            if (!(lane & 1)) xcpk[lane >> 1] = pack2(xc, oth);
            float othm = __shfl_xor(mr, 1);
            if (!(lane & 1)) ccm[32 + (lane >> 1)] = pack2(mr, othm);
            asm volatile("s_waitcnt lgkmcnt(0)" ::: "memory");   // same-wave LDS RAW

            float c0 = bfr_r, c1 = 0.f, c2 = 0.f, c3 = 0.f;
            #pragma unroll
            for (int k4 = 0; k4 < 8; k4++) {
                uint4 w = wfr4u[k4 * 64 + lane];
                uint4 xp = *(const uint4*)&xcpk[4 * k4];
                c0 = dot2f(w.x, xp.x, c0); c1 = dot2f(w.y, xp.y, c1);
                c2 = dot2f(w.z, xp.z, c2); c3 = dot2f(w.w, xp.w, c3);
            }
            float zh = (c0 + c1) + (c2 + c3);
            float ch = alr * zh + (1.f - alr) * xh;
            float cc = mr * xr + (1.f - mr) * ch;
            imp[t * NF + lane] = cc;
            lloss += (fabsf(xr - xh) + fabsf(xr - zh) + fabsf(xr - ch)) * mr * invr;
            float othc = __shfl_xor(cc, 1);
            if (!(lane & 1)) ccm[lane >> 1] = pack2(cc, othc);

            // stash h B-fragments for post-barrier MFMAs (hpk races after bar)
            #pragma unroll
            for (int c2 = 0; c2 < 4; c2++)
                bh0[c2] = *((const half8_t*)&hpk[16 * c2 + 4 * q]);
        }
        __syncthreads();   // bar_cc

        // ---- wave0: prefetch next-step inputs (hidden under gates phase) ----
        if (s == 0) {
            xr = vp[tn * NF + lane]; mr = mp[tn * NF + lane];
            alr = __half2float(alp[tn * NF + lane]); invr = invms[tn];
            #pragma unroll
            for (int g = 0; g < 4; g++) {
                acc[g] = bias_r[g];
                #pragma unroll
                for (int c2 = 0; c2 < 4; c2++)
                    acc[g] = mfma16(__builtin_bit_cast(half8_t, afr[g][4 + c2]), bh0[c2], acc[g]);
            }
        }

        // ---- gates cc/m-part MFMAs (all waves) ----
        {
            half8_t bc2[4];
            #pragma unroll
            for (int c2 = 0; c2 < 4; c2++)
                bc2[c2] = *((const half8_t*)&ccm[16 * c2 + 4 * q]);
            #pragma unroll
            for (int g = 0; g < 4; g++) {
                #pragma unroll
                for (int c2 = 0; c2 < 4; c2++)
                    acc[g] = mfma16(__builtin_bit_cast(half8_t, afr[g][c2]), bc2[c2], acc[g]);
            }
        }

        // ---- LSTM pointwise (wave-local; every lane has valid gates) ----
        {
            float2 g01 = __half22float2(__builtin_bit_cast(__half2, ghn.x));
            float2 g23 = __half22float2(__builtin_bit_cast(__half2, ghn.y));
            float hv[4];
            #pragma unroll
            for (int reg = 0; reg < 4; reg++) {
                float gi = acc[0][reg], gf = acc[1][reg];
                float gg = acc[2][reg], go = acc[3][reg];
                float cn = sigm(gf) * cst[reg] + sigm(gi) * tanh_fast(gg);
                cst[reg] = cn;
                hv[reg] = sigm(go) * tanh_fast(cn);
            }
            if (l15 == 0) {
                *(float4*)&hraw[16 * s + 4 * q] =
                    make_float4(hv[0], hv[1], hv[2], hv[3]);
                hpk[8 * s + 2 * q] = pack2(hv[0] * g01.x, hv[1] * g01.y);
                hpk[8 * s + 2 * q + 1] = pack2(hv[2] * g23.x, hv[3] * g23.y);
            }
        }
        __syncthreads();   // bar_h
    }

    // ---- finale: y_h, prediction, loss ----
    if (tid < 128) rbuf[tid] = hraw[tid] * W_out[tid];
    __syncthreads();
    if (tid < 64) {
        float yp = rbuf[tid] + rbuf[tid + 64];
        float ll = lloss;
        #pragma unroll
        for (int off = 32; off > 0; off >>= 1) {
            ll += __shfl_down(ll, off);
            yp += __shfl_down(yp, off);
        }
        if (tid == 0) {
            float yh = yp + b_out[0];
            d_out[1 + b] = 1.f / (1.f + expf(-yh));
            float lab = labels[b], istr = is_train[b];
            float maxv = fmaxf(-yh, 0.f);
            float yl = yh - yh * lab + maxv + logf(expf(-maxv) + expf(-yh - maxv));
            atomicAdd(d_out, ll * (1.f / (float)NT) + 0.3f * yl * istr * (*inv_istr));
        }
    }
}

// ---------------------------------------------------------------------------
extern "C" void kernel_launch(void* const* d_in, const int* in_sizes, int n_in,
                              void* d_out, int out_size, void* d_ws, size_t ws_size,
                              hipStream_t stream) {
    const float* values = (const float*)d_in[0];
    const float* masks = (const float*)d_in[1];
    const float* deltas = (const float*)d_in[2];
    const float* labels = (const float*)d_in[3];
    const float* is_train = (const float*)d_in[4];
    const float* W_dh = (const float*)d_in[5];
    const float* b_dh = (const float*)d_in[6];
    const float* W_dx = (const float*)d_in[7];
    const float* b_dx = (const float*)d_in[8];
    const float* W_hr = (const float*)d_in[9];
    const float* b_hr = (const float*)d_in[10];
    const float* W_fr = (const float*)d_in[11];
    const float* b_fr = (const float*)d_in[12];
    const float* W_wc = (const float*)d_in[13];
    const float* b_wc = (const float*)d_in[14];
    const float* W_ih = (const float*)d_in[15];
    const float* b_ih = (const float*)d_in[16];
    const float* W_hh = (const float*)d_in[17];
    const float* b_hh = (const float*)d_in[18];
    const float* W_out = (const float*)d_in[19];
    const float* b_out = (const float*)d_in[20];

    char* ws = (char*)d_ws;
    unsigned* wsu = (unsigned*)d_ws;
    const uint4* afrag_ws = (const uint4*)(ws + AFRAG_OFF);
    const uint4* whr_ws = (const uint4*)(ws + WHR_OFF);
    const uint4* wfr_ws = (const uint4*)(ws + WFR_OFF);
    float* invms = (float*)(ws + INVMS_OFF);
    float* inv_istr = (float*)(ws + ISTR_OFF);
    float* msum = (float*)(ws + MSUM_OFF);
    __half* gh_all = (__half*)(ws + GH_OFF);
    __half* al_all = (__half*)(ws + AL_OFF);
    float* out_f = (float*)d_out;

    prep_w<<<283, 256, 0, stream>>>(W_ih, W_hh, W_hr, W_fr, wsu, msum, out_f);
    ga_kernel<<<2048, 256, 0, stream>>>(deltas, masks, W_dh, b_dh, W_dx, b_dx,
                                        W_wc, b_wc, gh_all, al_all, msum);
    finalize_msum<<<1, 512, 0, stream>>>(msum, is_train, invms, inv_istr);
    main_kernel<<<NBATCH, 512, 0, stream>>>(values, masks, labels, is_train,
                                            b_hr, b_fr, b_ih, b_hh, W_out, b_out,
                                            afrag_ws, whr_ws, wfr_ws,
                                            invms, inv_istr, gh_all, al_all, out_f);
}

// Round 5
// 1624.148 us; speedup vs baseline: 1.4368x; 1.0255x over previous
//
#include <hip/hip_runtime.h>
#include <hip/hip_fp16.h>

// Problem: B=256, T=512, F=64, H=128  (GRU-D / BRITS-style recurrence)
// d_out (fp32): [0]=loss, [1..256]=predictions, [257..]=imputations [B,T,F]

#define NBATCH 256
#define NT 512
#define NF 64
#define NH 128

// ---- workspace byte offsets (16B aligned) ----
#define AFRAG_OFF 0u           // [256 tiles][64 lanes] uint4: MFMA A-frags of [W_ih|W_hh]
#define WHR_OFF   262144u      // [16][64]  uint4 packed f16 chunks of W_hr   ([k4][f])
#define WFR_OFF   278528u      // [8][64]   uint4 packed f16 chunks of W_fr (diag zeroed)
#define INVMS_OFF 286720u      // f32[512]
#define ISTR_OFF  288768u      // f32[1]
#define MSUM_OFF  289792u      // f32[512] raw mask sums (atomic accum, zeroed by prep_w)
#define GH_OFF    294912u      // f16 [B*T*128] gamma_h
#define AL_OFF    33849344u    // f16 [B*T*64]  alpha

typedef _Float16 half2_t __attribute__((ext_vector_type(2)));
typedef _Float16 half8_t __attribute__((ext_vector_type(8)));
typedef float float4_t __attribute__((ext_vector_type(4)));

__device__ __forceinline__ unsigned pack2(float a, float b) {
    __half2 h = __floats2half2_rn(a, b);
    return __builtin_bit_cast(unsigned, h);
}

__device__ __forceinline__ float dot2f(unsigned w, unsigned a, float acc) {
#if __has_builtin(__builtin_amdgcn_fdot2)
    return __builtin_amdgcn_fdot2(__builtin_bit_cast(half2_t, w),
                                  __builtin_bit_cast(half2_t, a), acc, false);
#else
    float2 wf = __half22float2(__builtin_bit_cast(__half2, w));
    float2 af = __half22float2(__builtin_bit_cast(__half2, a));
    return acc + wf.x * af.x + wf.y * af.y;
#endif
}

__device__ __forceinline__ float4_t mfma16(half8_t a, half8_t b, float4_t c) {
    return __builtin_amdgcn_mfma_f32_16x16x32_f16(a, b, c, 0, 0, 0);
}

__device__ __forceinline__ float sigm(float x) { return 1.f / (1.f + __expf(-x)); }
__device__ __forceinline__ float tanh_fast(float x) { return 1.f - 2.f / (__expf(2.f * x) + 1.f); }

// ---------------------------------------------------------------------------
// prep_w: (a) MFMA A-frags of G=[W_ih|W_hh] (512 rows x 256 k; k=[cc,m,h]),
// wave s, gate g, chunk c -> rows 128g+16s+(lane&15), k=32c+8*(lane>>4)+2comp.
// (b) W_hr / W_fr(zero-diag) f16x2 chunk layouts [k4][f].
// (c) zero msum[512] and d_out[0] (runs before ga_kernel's atomics).
// ---------------------------------------------------------------------------
__global__ __launch_bounds__(256) void prep_w(const float* __restrict__ Wih,
                                              const float* __restrict__ Whh,
                                              const float* __restrict__ Whr,
                                              const float* __restrict__ Wfr,
                                              unsigned* __restrict__ wsu,
                                              float* __restrict__ msum,
                                              float* __restrict__ d_out0) {
    int o = blockIdx.x * 256 + threadIdx.x;
    float v0, v1;
    if (o < 65536) {                      // A-fragments
        int comp = o & 3;
        int u4 = o >> 2;
        int lane = u4 & 63;
        int tile = u4 >> 6;               // = (s*4+g)*8 + c
        int c = tile & 7, g = (tile >> 3) & 3, s = tile >> 5;
        int row = 128 * g + 16 * s + (lane & 15);
        int kp = 16 * c + ((lane >> 4) << 2) + comp;
        int k0 = 2 * kp;
        if (k0 < 128) { v0 = Wih[row * 128 + k0]; v1 = Wih[row * 128 + k0 + 1]; }
        else          { v0 = Whh[row * 128 + k0 - 128]; v1 = Whh[row * 128 + k0 - 127]; }
    } else if (o < 69632) {               // W_hr [64][128] -> [k4][f]
        int o3 = o - 65536;
        int c = o3 & 3, f = (o3 >> 2) & 63, cb = o3 >> 8;
        int col = 8 * cb + 2 * c;
        v0 = Whr[f * 128 + col]; v1 = Whr[f * 128 + col + 1];
    } else if (o < 71680) {               // W_fr [64][64], zero diagonal
        int o4 = o - 69632;
        int c = o4 & 3, f = (o4 >> 2) & 63, cb = o4 >> 8;
        int col = 8 * cb + 2 * c;
        v0 = (col == f) ? 0.f : Wfr[f * 64 + col];
        v1 = (col + 1 == f) ? 0.f : Wfr[f * 64 + col + 1];
    } else {
        int idx = o - 71680;
        if (idx < 512) msum[idx] = 0.f;
        else if (idx == 512) *d_out0 = 0.f;
        return;
    }
    wsu[o] = pack2(v0, v1);
}

// ---------------------------------------------------------------------------
// finalize_msum: invms[t] = 1/(msum[t]+eps); inv_istr = 1/(sum is_train + eps).
// ---------------------------------------------------------------------------
__global__ __launch_bounds__(512) void finalize_msum(const float* __restrict__ msum,
                                                     const float* __restrict__ is_train,
                                                     float* __restrict__ invms,
                                                     float* __restrict__ inv_istr) {
    __shared__ float red[256];
    int tid = threadIdx.x;
    invms[tid] = 1.f / (msum[tid] + 1e-5f);
    if (tid < 256) red[tid] = is_train[tid];
    __syncthreads();
    for (int off = 128; off > 0; off >>= 1) {
        if (tid < off) red[tid] += red[tid + off];
        __syncthreads();
    }
    if (tid == 0) *inv_istr = 1.f / (red[0] + 1e-5f);
}

// ---------------------------------------------------------------------------
// ga_kernel: precompute gamma_h[b,t,128], alpha[b,t,64] (f16), and atomically
// accumulate per-t mask sums. grid 2048 x 256, 64 (b,t) pairs per block.
// ---------------------------------------------------------------------------
__global__ __launch_bounds__(256) void ga_kernel(const float* __restrict__ deltas,
                                                 const float* __restrict__ masks,
                                                 const float* __restrict__ Wdh,
                                                 const float* __restrict__ bdh,
                                                 const float* __restrict__ Wdx,
                                                 const float* __restrict__ bdx,
                                                 const float* __restrict__ Wwc,
                                                 const float* __restrict__ bwc,
                                                 __half* __restrict__ gh_all,
                                                 __half* __restrict__ al_all,
                                                 float* __restrict__ msum) {
    __shared__ unsigned wdhpk[32 * 128];   // [k2][j]
    __shared__ unsigned wwcpk[64 * 64];    // [k2][f]
    __shared__ float sbdh[128], sbdx[64], swdx[64], sbwc[64];
    __shared__ float dbuf[64];
    __shared__ __align__(16) unsigned dpk[32], gxpk[32], mpk2[32];
    int tid = threadIdx.x;

    for (int o = tid; o < 4096; o += 256) {
        int j = o & 127, k2 = o >> 7;
        wdhpk[o] = pack2(Wdh[j * 64 + 2 * k2], Wdh[j * 64 + 2 * k2 + 1]);
    }
    for (int o = tid; o < 4096; o += 256) {
        int f = o & 63, k2 = o >> 6;
        wwcpk[o] = pack2(Wwc[f * 128 + 2 * k2], Wwc[f * 128 + 2 * k2 + 1]);
    }
    if (tid < 128) sbdh[tid] = bdh[tid];
    if (tid < 64) {
        sbdx[tid] = bdx[tid];
        swdx[tid] = Wdx[tid * 65];
        sbwc[tid] = bwc[tid];
    }
    __syncthreads();

    for (int i = 0; i < 64; i++) {
        int p = blockIdx.x * 64 + i;           // p = b*T + t
        if (tid < 32) {
            float2 dv = ((const float2*)(deltas + (size_t)p * NF))[tid];
            dbuf[2 * tid] = dv.x; dbuf[2 * tid + 1] = dv.y;
            dpk[tid] = pack2(dv.x, dv.y);
        } else if (tid < 64) {
            int q = tid - 32;
            float2 mv = ((const float2*)(masks + (size_t)p * NF))[q];
            mpk2[q] = pack2(mv.x, mv.y);
            float sm = mv.x + mv.y;            // per-t mask sum (ints: order-safe)
            #pragma unroll
            for (int off = 16; off > 0; off >>= 1) sm += __shfl_xor(sm, off);
            if (tid == 32) atomicAdd(&msum[p & (NT - 1)], sm);
        }
        __syncthreads();
        if (tid < 64) {
            float gx = __expf(-fmaxf(dbuf[tid] * swdx[tid] + sbdx[tid], 0.f));
            float oth = __shfl_xor(gx, 1);
            if (!(tid & 1)) gxpk[tid >> 1] = pack2(gx, oth);
        }
        __syncthreads();
        if (tid < 128) {
            float a0 = sbdh[tid], a1 = 0.f;
            #pragma unroll
            for (int k8 = 0; k8 < 8; k8++) {
                uint4 dp = *(const uint4*)&dpk[4 * k8];
                a0 = dot2f(wdhpk[(4 * k8 + 0) * 128 + tid], dp.x, a0);
                a1 = dot2f(wdhpk[(4 * k8 + 1) * 128 + tid], dp.y, a1);
                a0 = dot2f(wdhpk[(4 * k8 + 2) * 128 + tid], dp.z, a0);
                a1 = dot2f(wdhpk[(4 * k8 + 3) * 128 + tid], dp.w, a1);
            }
            gh_all[(size_t)p * NH + tid] = __float2half(__expf(-fmaxf(a0 + a1, 0.f)));
        } else if (tid < 192) {
            int f = tid - 128;
            float a0 = sbwc[f], a1 = 0.f;
            #pragma unroll
            for (int k8 = 0; k8 < 8; k8++) {
                uint4 gp = *(const uint4*)&gxpk[4 * k8];
                a0 = dot2f(wwcpk[(4 * k8 + 0) * 64 + f], gp.x, a0);
                a1 = dot2f(wwcpk[(4 * k8 + 1) * 64 + f], gp.y, a1);
                a0 = dot2f(wwcpk[(4 * k8 + 2) * 64 + f], gp.z, a0);
                a1 = dot2f(wwcpk[(4 * k8 + 3) * 64 + f], gp.w, a1);
            }
            #pragma unroll
            for (int k8 = 0; k8 < 8; k8++) {
                uint4 mp = *(const uint4*)&mpk2[4 * k8];
                a0 = dot2f(wwcpk[(32 + 4 * k8 + 0) * 64 + f], mp.x, a0);
                a1 = dot2f(wwcpk[(32 + 4 * k8 + 1) * 64 + f], mp.y, a1);
                a0 = dot2f(wwcpk[(32 + 4 * k8 + 2) * 64 + f], mp.z, a0);
                a1 = dot2f(wwcpk[(32 + 4 * k8 + 3) * 64 + f], mp.w, a1);
            }
            al_all[(size_t)p * NF + f] = __float2half(a0 + a1);
        }
        __syncthreads();
    }
}

// ---------------------------------------------------------------------------
// main_kernel: one block per batch element, 512 threads (8 waves), 2 barriers
// per step. Gate weights: 128 dwords/thread loaded ONCE via volatile loads
// (non-rematerializable) -> allocator parks them in AGPRs; MFMA reads A
// operands natively from AGPRs (zero per-step cost). NO in-loop asm pin
// (R4 failure mode: 256 accvgpr copies/wave/step + 32 sched fences).
// All waves issue h-part MFMAs at loop top; wave0's serial x_h->z_h chain
// overlaps their latency (acc not read until after bar_cc).
// ---------------------------------------------------------------------------
__global__ __attribute__((amdgpu_waves_per_eu(2, 2))) __launch_bounds__(512)
void main_kernel(
    const float* __restrict__ values, const float* __restrict__ masks,
    const float* __restrict__ labels, const float* __restrict__ is_train,
    const float* __restrict__ b_hr, const float* __restrict__ b_fr,
    const float* __restrict__ b_ih, const float* __restrict__ b_hh,
    const float* __restrict__ W_out, const float* __restrict__ b_out,
    const uint4* __restrict__ afrag_ws, const uint4* __restrict__ whr_ws,
    const uint4* __restrict__ wfr_ws,
    const float* __restrict__ invms, const float* __restrict__ inv_istr,
    const __half* __restrict__ gh_all, const __half* __restrict__ al_all,
    float* __restrict__ d_out) {
    __shared__ __align__(16) uint4 whr4u[1024];      // 16 KB  [k4][f]
    __shared__ __align__(16) uint4 wfr4u[512];       // 8 KB   [k4][f]
    __shared__ __align__(16) unsigned hpk[64];       // decayed h, f16x2
    __shared__ __align__(16) unsigned ccm[64];       // [cc(32) | m(32)] f16x2
    __shared__ __align__(16) unsigned xcpk[32];      // x_c f16x2
    __shared__ float hraw[128];
    __shared__ float rbuf[128];

    const int tid = threadIdx.x;
    const int b = blockIdx.x;
    const int lane = tid & 63;
    const int s = tid >> 6;
    const int q = lane >> 4;          // 0..3
    const int l15 = lane & 15;

    // ---- A-fragments: loaded once via volatile (cannot be rematerialized;
    // free to live in AGPRs, where MFMA reads them natively) ----
    uint4 afr[4][8];
    {
        const volatile unsigned* av = (const volatile unsigned*)afrag_ws;
        #pragma unroll
        for (int g = 0; g < 4; g++)
            #pragma unroll
            for (int c = 0; c < 8; c++) {
                int base = ((((s * 4 + g) * 8) + c) * 64 + lane) * 4;
                afr[g][c].x = av[base + 0];
                afr[g][c].y = av[base + 1];
                afr[g][c].z = av[base + 2];
                afr[g][c].w = av[base + 3];
            }
    }

    float4_t bias_r[4];
    #pragma unroll
    for (int g = 0; g < 4; g++)
        #pragma unroll
        for (int reg = 0; reg < 4; reg++) {
            int row = 128 * g + 16 * s + 4 * q + reg;
            bias_r[g][reg] = b_ih[row] + b_hh[row];
        }

    for (int o = tid; o < 1024; o += 512) whr4u[o] = whr_ws[o];
    if (tid < 512) wfr4u[tid] = wfr_ws[tid];
    if (tid < 64) hpk[tid] = 0u;

    const float* vp = values + (size_t)b * NT * NF;
    const float* mp = masks + (size_t)b * NT * NF;
    const __half* alp = al_all + (size_t)b * NT * NF;
    const __half* ghp = gh_all + (size_t)b * NT * NH;
    float* imp = d_out + 257 + (size_t)b * NT * NF;

    float cst[4] = {0.f, 0.f, 0.f, 0.f};   // LSTM c-state (wave-local)
    float lloss = 0.f;
    float bhr_r = 0.f, bfr_r = 0.f;
    float xr = 0.f, mr = 0.f, alr = 0.f, invr = 0.f;
    if (s == 0) {
        bhr_r = b_hr[lane]; bfr_r = b_fr[lane];
        xr = vp[lane]; mr = mp[lane];
        alr = __half2float(alp[lane]); invr = invms[0];
    }
    __syncthreads();

    for (int t = 0; t < NT; t++) {
        int tn = (t + 1 < NT) ? (t + 1) : (NT - 1);
        // gamma_h(t+1) for this wave's 4 elements (quad-uniform address)
        uint2 ghn = *(const uint2*)(ghp + (size_t)tn * NH + 16 * s + 4 * q);

        // ---- h-part MFMAs (all waves; results consumed after bar_cc) ----
        float4_t acc[4];
        {
            half8_t bh[4];
            #pragma unroll
            for (int c2 = 0; c2 < 4; c2++)
                bh[c2] = *((const half8_t*)&hpk[16 * c2 + 4 * q]);
            #pragma unroll
            for (int g = 0; g < 4; g++) {
                acc[g] = bias_r[g];
                #pragma unroll
                for (int c2 = 0; c2 < 4; c2++)
                    acc[g] = mfma16(__builtin_bit_cast(half8_t, afr[g][4 + c2]), bh[c2], acc[g]);
            }
        }

        // ---- wave0 serial chain: x_h -> x_c -> z_h -> c_c ----
        if (s == 0) {
            float a0 = bhr_r, a1 = 0.f, a2 = 0.f, a3 = 0.f;
            #pragma unroll
            for (int k4 = 0; k4 < 16; k4++) {
                uint4 w = whr4u[k4 * 64 + lane];
                uint4 hp = *(const uint4*)&hpk[4 * k4];
                a0 = dot2f(w.x, hp.x, a0); a1 = dot2f(w.y, hp.y, a1);
                a2 = dot2f(w.z, hp.z, a2); a3 = dot2f(w.w, hp.w, a3);
            }
            float xh = (a0 + a1) + (a2 + a3);
            float xc = mr * xr + (1.f - mr) * xh;
            float oth = __shfl_xor(xc, 1);
            if (!(lane & 1)) xcpk[lane >> 1] = pack2(xc, oth);
            float othm = __shfl_xor(mr, 1);
            if (!(lane & 1)) ccm[32 + (lane >> 1)] = pack2(mr, othm);
            asm volatile("s_waitcnt lgkmcnt(0)" ::: "memory");   // same-wave LDS RAW

            float c0 = bfr_r, c1 = 0.f, c2 = 0.f, c3 = 0.f;
            #pragma unroll
            for (int k4 = 0; k4 < 8; k4++) {
                uint4 w = wfr4u[k4 * 64 + lane];
                uint4 xp = *(const uint4*)&xcpk[4 * k4];
                c0 = dot2f(w.x, xp.x, c0); c1 = dot2f(w.y, xp.y, c1);
                c2 = dot2f(w.z, xp.z, c2); c3 = dot2f(w.w, xp.w, c3);
            }
            float zh = (c0 + c1) + (c2 + c3);
            float ch = alr * zh + (1.f - alr) * xh;
            float cc = mr * xr + (1.f - mr) * ch;
            imp[t * NF + lane] = cc;
            lloss += (fabsf(xr - xh) + fabsf(xr - zh) + fabsf(xr - ch)) * mr * invr;
            float othc = __shfl_xor(cc, 1);
            if (!(lane & 1)) ccm[lane >> 1] = pack2(cc, othc);
        }
        __syncthreads();   // bar_cc

        // ---- wave0: prefetch next-step inputs (hidden under gates phase) ----
        if (s == 0) {
            xr = vp[tn * NF + lane]; mr = mp[tn * NF + lane];
            alr = __half2float(alp[tn * NF + lane]); invr = invms[tn];
        }

        // ---- gates cc/m-part MFMAs (all waves) ----
        {
            half8_t bc2[4];
            #pragma unroll
            for (int c2 = 0; c2 < 4; c2++)
                bc2[c2] = *((const half8_t*)&ccm[16 * c2 + 4 * q]);
            #pragma unroll
            for (int g = 0; g < 4; g++) {
                #pragma unroll
                for (int c2 = 0; c2 < 4; c2++)
                    acc[g] = mfma16(__builtin_bit_cast(half8_t, afr[g][c2]), bc2[c2], acc[g]);
            }
        }

        // ---- LSTM pointwise (wave-local; every lane has valid gates) ----
        {
            float2 g01 = __half22float2(__builtin_bit_cast(__half2, ghn.x));
            float2 g23 = __half22float2(__builtin_bit_cast(__half2, ghn.y));
            float hv[4];
            #pragma unroll
            for (int reg = 0; reg < 4; reg++) {
                float gi = acc[0][reg], gf = acc[1][reg];
                float gg = acc[2][reg], go = acc[3][reg];
                float cn = sigm(gf) * cst[reg] + sigm(gi) * tanh_fast(gg);
                cst[reg] = cn;
                hv[reg] = sigm(go) * tanh_fast(cn);
            }
            if (l15 == 0) {
                *(float4*)&hraw[16 * s + 4 * q] =
                    make_float4(hv[0], hv[1], hv[2], hv[3]);
                hpk[8 * s + 2 * q] = pack2(hv[0] * g01.x, hv[1] * g01.y);
                hpk[8 * s + 2 * q + 1] = pack2(hv[2] * g23.x, hv[3] * g23.y);
            }
        }
        __syncthreads();   // bar_h
    }

    // ---- finale: y_h, prediction, loss ----
    if (tid < 128) rbuf[tid] = hraw[tid] * W_out[tid];
    __syncthreads();
    if (tid < 64) {
        float yp = rbuf[tid] + rbuf[tid + 64];
        float ll = lloss;
        #pragma unroll
        for (int off = 32; off > 0; off >>= 1) {
            ll += __shfl_down(ll, off);
            yp += __shfl_down(yp, off);
        }
        if (tid == 0) {
            float yh = yp + b_out[0];
            d_out[1 + b] = 1.f / (1.f + expf(-yh));
            float lab = labels[b], istr = is_train[b];
            float maxv = fmaxf(-yh, 0.f);
            float yl = yh - yh * lab + maxv + logf(expf(-maxv) + expf(-yh - maxv));
            atomicAdd(d_out, ll * (1.f / (float)NT) + 0.3f * yl * istr * (*inv_istr));
        }
    }
}

// ---------------------------------------------------------------------------
extern "C" void kernel_launch(void* const* d_in, const int* in_sizes, int n_in,
                              void* d_out, int out_size, void* d_ws, size_t ws_size,
                              hipStream_t stream) {
    const float* values = (const float*)d_in[0];
    const float* masks = (const float*)d_in[1];
    const float* deltas = (const float*)d_in[2];
    const float* labels = (const float*)d_in[3];
    const float* is_train = (const float*)d_in[4];
    const float* W_dh = (const float*)d_in[5];
    const float* b_dh = (const float*)d_in[6];
    const float* W_dx = (const float*)d_in[7];
    const float* b_dx = (const float*)d_in[8];
    const float* W_hr = (const float*)d_in[9];
    const float* b_hr = (const float*)d_in[10];
    const float* W_fr = (const float*)d_in[11];
    const float* b_fr = (const float*)d_in[12];
    const float* W_wc = (const float*)d_in[13];
    const float* b_wc = (const float*)d_in[14];
    const float* W_ih = (const float*)d_in[15];
    const float* b_ih = (const float*)d_in[16];
    const float* W_hh = (const float*)d_in[17];
    const float* b_hh = (const float*)d_in[18];
    const float* W_out = (const float*)d_in[19];
    const float* b_out = (const float*)d_in[20];

    char* ws = (char*)d_ws;
    unsigned* wsu = (unsigned*)d_ws;
    const uint4* afrag_ws = (const uint4*)(ws + AFRAG_OFF);
    const uint4* whr_ws = (const uint4*)(ws + WHR_OFF);
    const uint4* wfr_ws = (const uint4*)(ws + WFR_OFF);
    float* invms = (float*)(ws + INVMS_OFF);
    float* inv_istr = (float*)(ws + ISTR_OFF);
    float* msum = (float*)(ws + MSUM_OFF);
    __half* gh_all = (__half*)(ws + GH_OFF);
    __half* al_all = (__half*)(ws + AL_OFF);
    float* out_f = (float*)d_out;

    prep_w<<<283, 256, 0, stream>>>(W_ih, W_hh, W_hr, W_fr, wsu, msum, out_f);
    ga_kernel<<<2048, 256, 0, stream>>>(deltas, masks, W_dh, b_dh, W_dx, b_dx,
                                        W_wc, b_wc, gh_all, al_all, msum);
    finalize_msum<<<1, 512, 0, stream>>>(msum, is_train, invms, inv_istr);
    main_kernel<<<NBATCH, 512, 0, stream>>>(values, masks, labels, is_train,
                                            b_hr, b_fr, b_ih, b_hh, W_out, b_out,
                                            afrag_ws, whr_ws, wfr_ws,
                                            invms, inv_istr, gh_all, al_all, out_f);
}